// Round 5
// baseline (702.380 us; speedup 1.0000x reference)
//
#include <hip/hip_runtime.h>
#include <cstddef>
#include <cstdint>

#define CLEN 1024
#define QLEN 128
#define DDIM 512
#define NBATCH 64
#define NEGINF (-1e30f)

typedef float4 f4;

__device__ __forceinline__ float comp4(const f4 v, int m) {
  return m == 0 ? v.x : (m == 1 ? v.y : (m == 2 ? v.z : v.w));
}

// ---------------- K1: sim, row-softmax, c2q, out chunks 0/1, s_max ----------
// grid (CLEN/64, NBATCH), block 256. Thread (ty=tid>>4, tx=tid&15):
// rows i = ty*4+r (r<4), cols j = tx*4+s + g*64 (g<2, s<4)  -> 4x8 acc tile.
__global__ __launch_bounds__(256, 2)
void k1_sim_c2q(const float* __restrict__ qg, const int* __restrict__ qmk_g,
                const float* __restrict__ cg, const float* __restrict__ wg,
                const float* __restrict__ bg, float* __restrict__ out,
                float* __restrict__ smax_ws)
{
  __shared__ float lds[12736];
  float* const c_t  = lds;           // [64][36]  raw c tile (k-padded)
  float* const q_t  = lds + 2304;    // [32][128] k-major, premultiplied by w3
  float* const w_s  = lds + 6400;    // [1536]    w staged
  float* const p_t  = lds;           // [64][132] P (overlays phase-A bufs)
  float* const qc_t = lds + 8448;    // [32][128] q tile for phase C (j-major)
  float* const cw1s = lds + 12544;   // [64]
  float* const qw2s = lds + 12608;   // [128]

  const int tid = threadIdx.x;
  const int tx = tid & 15, ty = tid >> 4;
  const int b  = blockIdx.y;
  const int i0 = blockIdx.x * 64;

  const float* cb = cg + (size_t)(b * CLEN + i0) * DDIM;
  const float* qb = qg + (size_t)b * QLEN * DDIM;

  #pragma unroll
  for (int it = 0; it < 6; ++it) w_s[tid + it * 256] = wg[tid + it * 256];

  float acc[4][8];
  #pragma unroll
  for (int r = 0; r < 4; ++r)
    #pragma unroll
    for (int s = 0; s < 8; ++s) acc[r][s] = 0.f;

  float cw1p0 = 0.f, cw1p1 = 0.f, qw2p = 0.f;

  // ---------------- phase A: sim = (c .* w3) @ q^T ----------------
  for (int kt = 0; kt < 16; ++kt) {
    __syncthreads();
    {  // stage c tile (raw) + cw1 partials; thread -> (row=tid>>3, f=tid&7)
      const int row0 = tid >> 3, f = tid & 7;
      const int kb = kt * 32 + f * 4;
      f4 v = *(const f4*)(cb + (size_t)row0 * DDIM + kb);
      cw1p0 += v.x * w_s[kb] + v.y * w_s[kb + 1] + v.z * w_s[kb + 2] + v.w * w_s[kb + 3];
      *(f4*)(c_t + row0 * 36 + f * 4) = v;
      f4 v2 = *(const f4*)(cb + (size_t)(row0 + 32) * DDIM + kb);
      cw1p1 += v2.x * w_s[kb] + v2.y * w_s[kb + 1] + v2.z * w_s[kb + 2] + v2.w * w_s[kb + 3];
      *(f4*)(c_t + (row0 + 32) * 36 + f * 4) = v2;
    }
    {  // stage q tile: transpose to k-major, scale by w3, + qw2 partial
      const int j = tid >> 1;
      #pragma unroll
      for (int it = 0; it < 4; ++it) {
        const int kq = (tid & 1) + it * 2;
        const int kb = kt * 32 + kq * 4;
        f4 v = *(const f4*)(qb + (size_t)j * DDIM + kb);
        qw2p += v.x * w_s[512 + kb] + v.y * w_s[512 + kb + 1] +
                v.z * w_s[512 + kb + 2] + v.w * w_s[512 + kb + 3];
        v.x *= w_s[1024 + kb];     v.y *= w_s[1024 + kb + 1];
        v.z *= w_s[1024 + kb + 2]; v.w *= w_s[1024 + kb + 3];
        q_t[(kq * 4 + 0) * 128 + j] = v.x;
        q_t[(kq * 4 + 1) * 128 + j] = v.y;
        q_t[(kq * 4 + 2) * 128 + j] = v.z;
        q_t[(kq * 4 + 3) * 128 + j] = v.w;
      }
    }
    __syncthreads();
    #pragma unroll
    for (int k4 = 0; k4 < 8; ++k4) {
      f4 cv[4];
      #pragma unroll
      for (int r = 0; r < 4; ++r)
        cv[r] = *(const f4*)(c_t + (ty * 4 + r) * 36 + k4 * 4);
      #pragma unroll
      for (int m = 0; m < 4; ++m) {
        const int krow = (k4 * 4 + m) * 128;
        f4 v0 = *(const f4*)(q_t + krow + tx * 4);
        f4 v1 = *(const f4*)(q_t + krow + tx * 4 + 64);
        #pragma unroll
        for (int r = 0; r < 4; ++r) {
          const float a = comp4(cv[r], m);
          acc[r][0] += a * v0.x; acc[r][1] += a * v0.y;
          acc[r][2] += a * v0.z; acc[r][3] += a * v0.w;
          acc[r][4] += a * v1.x; acc[r][5] += a * v1.y;
          acc[r][6] += a * v1.z; acc[r][7] += a * v1.w;
        }
      }
    }
  }

  // reduce cw1/qw2 partials into LDS
  cw1p0 += __shfl_xor(cw1p0, 1); cw1p0 += __shfl_xor(cw1p0, 2); cw1p0 += __shfl_xor(cw1p0, 4);
  cw1p1 += __shfl_xor(cw1p1, 1); cw1p1 += __shfl_xor(cw1p1, 2); cw1p1 += __shfl_xor(cw1p1, 4);
  qw2p  += __shfl_xor(qw2p, 1);
  if ((tid & 7) == 0) { cw1s[tid >> 3] = cw1p0; cw1s[(tid >> 3) + 32] = cw1p1; }
  if ((tid & 1) == 0) qw2s[tid >> 1] = qw2p;
  __syncthreads();

  // ---------------- phase B: row softmax over j (16-lane groups) -----------
  const float bias = bg[0];
  float qw2v[8]; int qm[8];
  #pragma unroll
  for (int g = 0; g < 2; ++g)
    #pragma unroll
    for (int s = 0; s < 4; ++s) {
      const int j = tx * 4 + s + g * 64;
      qw2v[g * 4 + s] = qw2s[j];
      qm[g * 4 + s] = qmk_g[b * QLEN + j];
    }

  #pragma unroll
  for (int r = 0; r < 4; ++r) {
    const float c1 = cw1s[ty * 4 + r] + bias;
    float mraw = -INFINITY, mmsk = -INFINITY;
    #pragma unroll
    for (int e = 0; e < 8; ++e) {
      float v = acc[r][e] + c1 + qw2v[e];
      acc[r][e] = v;
      mraw = fmaxf(mraw, v);
      mmsk = fmaxf(mmsk, qm[e] ? v : v + NEGINF);
    }
    #pragma unroll
    for (int off = 1; off < 16; off <<= 1) {
      mraw = fmaxf(mraw, __shfl_xor(mraw, off));
      mmsk = fmaxf(mmsk, __shfl_xor(mmsk, off));
    }
    float ssum = 0.f;
    #pragma unroll
    for (int e = 0; e < 8; ++e) {
      const float vm = qm[e] ? acc[r][e] : acc[r][e] + NEGINF;
      const float p = __expf(vm - mmsk);
      acc[r][e] = p; ssum += p;
    }
    #pragma unroll
    for (int off = 1; off < 16; off <<= 1) ssum += __shfl_xor(ssum, off);
    const float inv = 1.0f / ssum;
    #pragma unroll
    for (int e = 0; e < 8; ++e) acc[r][e] *= inv;
    if (tx == 0) smax_ws[b * CLEN + i0 + ty * 4 + r] = mraw;
  }

  // P -> LDS (phase-A buffers are dead)
  #pragma unroll
  for (int r = 0; r < 4; ++r) {
    *(f4*)(p_t + (ty * 4 + r) * 132 + tx * 4) =
        make_float4(acc[r][0], acc[r][1], acc[r][2], acc[r][3]);
    *(f4*)(p_t + (ty * 4 + r) * 132 + tx * 4 + 64) =
        make_float4(acc[r][4], acc[r][5], acc[r][6], acc[r][7]);
  }

  // ---------------- phase C: c2q = P @ q, fused epilogue -------------------
  float* outb = out + (size_t)(b * CLEN + i0) * 1536;
  for (int nc = 0; nc < 4; ++nc) {
    const int n0 = nc * 128;
    float a2[4][8];
    #pragma unroll
    for (int r = 0; r < 4; ++r)
      #pragma unroll
      for (int s = 0; s < 8; ++s) a2[r][s] = 0.f;

    for (int jt = 0; jt < 4; ++jt) {
      __syncthreads();
      #pragma unroll
      for (int it = 0; it < 4; ++it) {
        const int idx = tid + it * 256;
        const int jj = idx >> 5, f = idx & 31;
        f4 v = *(const f4*)(qb + (size_t)(jt * 32 + jj) * DDIM + n0 + f * 4);
        *(f4*)(qc_t + jj * 128 + f * 4) = v;
      }
      __syncthreads();
      #pragma unroll
      for (int j4 = 0; j4 < 8; ++j4) {
        f4 pv[4];
        #pragma unroll
        for (int r = 0; r < 4; ++r)
          pv[r] = *(const f4*)(p_t + (ty * 4 + r) * 132 + jt * 32 + j4 * 4);
        #pragma unroll
        for (int m = 0; m < 4; ++m) {
          const int krow = (j4 * 4 + m) * 128;
          f4 v0 = *(const f4*)(qc_t + krow + tx * 4);
          f4 v1 = *(const f4*)(qc_t + krow + tx * 4 + 64);
          #pragma unroll
          for (int r = 0; r < 4; ++r) {
            const float a = comp4(pv[r], m);
            a2[r][0] += a * v0.x; a2[r][1] += a * v0.y;
            a2[r][2] += a * v0.z; a2[r][3] += a * v0.w;
            a2[r][4] += a * v1.x; a2[r][5] += a * v1.y;
            a2[r][6] += a * v1.z; a2[r][7] += a * v1.w;
          }
        }
      }
    }
    // epilogue: out chunk0 = c2q, chunk1 = c .* c2q
    #pragma unroll
    for (int r = 0; r < 4; ++r) {
      const int i = ty * 4 + r;
      #pragma unroll
      for (int g = 0; g < 2; ++g) {
        const int d = n0 + tx * 4 + g * 64;
        const f4 cv = *(const f4*)(cb + (size_t)i * DDIM + d);
        const f4 av = make_float4(a2[r][g * 4], a2[r][g * 4 + 1],
                                  a2[r][g * 4 + 2], a2[r][g * 4 + 3]);
        *(f4*)(outb + (size_t)i * 1536 + d) = av;
        const f4 mv = make_float4(cv.x * av.x, cv.y * av.y, cv.z * av.z, cv.w * av.w);
        *(f4*)(outb + (size_t)i * 1536 + 512 + d) = mv;
      }
    }
  }
}

// ---------------- K2pre: per-batch softmax stats over s_max -----------------
__global__ __launch_bounds__(256)
void k2_bstats(const float* __restrict__ smax_ws, const int* __restrict__ cmk_g,
               float* __restrict__ MS)
{
  __shared__ float red[8];
  const int b = blockIdx.x, tid = threadIdx.x;
  float v[4], m = -INFINITY;
  #pragma unroll
  for (int it = 0; it < 4; ++it) {
    const int i = tid + it * 256;
    float x = smax_ws[b * CLEN + i];
    if (cmk_g[b * CLEN + i] == 0) x += NEGINF;
    v[it] = x;
    m = fmaxf(m, x);
  }
  #pragma unroll
  for (int off = 1; off < 64; off <<= 1) m = fmaxf(m, __shfl_xor(m, off));
  if ((tid & 63) == 0) red[tid >> 6] = m;
  __syncthreads();
  m = fmaxf(fmaxf(red[0], red[1]), fmaxf(red[2], red[3]));
  float s = 0.f;
  #pragma unroll
  for (int it = 0; it < 4; ++it) s += __expf(v[it] - m);
  #pragma unroll
  for (int off = 1; off < 64; off <<= 1) s += __shfl_xor(s, off);
  if ((tid & 63) == 0) red[4 + (tid >> 6)] = s;
  __syncthreads();
  if (tid == 0) { MS[b * 2] = m; MS[b * 2 + 1] = red[4] + red[5] + red[6] + red[7]; }
}

// ---------------- K2a: c_dash = dist @ c (atomic partial sums) --------------
__global__ __launch_bounds__(256)
void k2_cdash(const float* __restrict__ smax_ws, const int* __restrict__ cmk_g,
              const float* __restrict__ cg, const float* __restrict__ MS,
              float* __restrict__ cdash)
{
  __shared__ float dist[128];
  const int b = blockIdx.y, sl = blockIdx.x, tid = threadIdx.x;
  const float M = MS[b * 2], S = MS[b * 2 + 1];
  if (tid < 128) {
    const int i = sl * 128 + tid;
    float x = smax_ws[b * CLEN + i];
    if (cmk_g[b * CLEN + i] == 0) x += NEGINF;
    dist[tid] = __expf(x - M) / S;
  }
  __syncthreads();
  const float* cb = cg + (size_t)(b * CLEN + sl * 128) * DDIM;
  float a0 = 0.f, a1 = 0.f;
  #pragma unroll 4
  for (int r = 0; r < 128; ++r) {
    const float wv = dist[r];
    a0 += wv * cb[(size_t)r * DDIM + tid];
    a1 += wv * cb[(size_t)r * DDIM + 256 + tid];
  }
  atomicAdd(&cdash[b * DDIM + tid], a0);
  atomicAdd(&cdash[b * DDIM + 256 + tid], a1);
}

// ---------------- K2b: out chunk2 = c .* c_dash -----------------------------
__global__ __launch_bounds__(256)
void k2_out2(const float* __restrict__ cg, const float* __restrict__ cdash,
             float* __restrict__ out)
{
  const long long N4 = (long long)NBATCH * CLEN * (DDIM / 4);
  const f4* c4 = (const f4*)cg;
  const f4* d4p = (const f4*)cdash;
  f4* o4 = (f4*)out;
  for (long long idx = (long long)blockIdx.x * blockDim.x + threadIdx.x;
       idx < N4; idx += (long long)gridDim.x * blockDim.x) {
    const long long bi = idx >> 7;         // b*CLEN + i
    const int dd = (int)(idx & 127);       // d/4
    const int bb = (int)(idx >> 17);       // batch
    const f4 cv = c4[idx];
    const f4 dv = d4p[(bb << 7) + dd];
    f4 o;
    o.x = cv.x * dv.x; o.y = cv.y * dv.y; o.z = cv.z * dv.z; o.w = cv.w * dv.w;
    o4[bi * 384 + 256 + dd] = o;           // row stride 1536/4, chunk2 at 1024/4
  }
}

extern "C" void kernel_launch(void* const* d_in, const int* in_sizes, int n_in,
                              void* d_out, int out_size, void* d_ws, size_t ws_size,
                              hipStream_t stream)
{
  (void)in_sizes; (void)n_in; (void)out_size; (void)ws_size;
  const float* qg  = (const float*)d_in[0];
  const int*   qmk = (const int*)d_in[1];
  const float* cg  = (const float*)d_in[2];
  const int*   cmk = (const int*)d_in[3];
  const float* wg  = (const float*)d_in[4];
  const float* bg  = (const float*)d_in[5];
  float* out = (float*)d_out;

  float* smax_ws = (float*)d_ws;                 // 64*1024 floats
  float* MS      = smax_ws + NBATCH * CLEN;      // 128 floats (M,S per batch)
  float* cdash   = MS + 2 * NBATCH;              // 64*512 floats

  hipMemsetAsync(cdash, 0, (size_t)NBATCH * DDIM * sizeof(float), stream);
  k1_sim_c2q<<<dim3(CLEN / 64, NBATCH), 256, 0, stream>>>(qg, qmk, cg, wg, bg, out, smax_ws);
  k2_bstats<<<NBATCH, 256, 0, stream>>>(smax_ws, cmk, MS);
  k2_cdash<<<dim3(8, NBATCH), 256, 0, stream>>>(smax_ws, cmk, cg, MS, cdash);
  k2_out2<<<2048, 256, 0, stream>>>(cg, cdash, out);
}